// Round 5
// baseline (369.146 us; speedup 1.0000x reference)
//
#include <hip/hip_runtime.h>

typedef unsigned short u16;
typedef unsigned int u32;
typedef __attribute__((ext_vector_type(8))) short bfrag_t;   // 8 bf16 (4 VGPRs)
typedef __attribute__((ext_vector_type(4))) float accfrag_t; // 4 fp32

// ---------- bf16 helpers (RNE) ----------
__device__ __forceinline__ u16 f2b(float f) {
    u32 u = __float_as_uint(f);
    u32 r = (u + 0x7FFFu + ((u >> 16) & 1u)) >> 16;
    return (u16)r;
}
__device__ __forceinline__ float b2f(u16 b) {
    return __uint_as_float(((u32)b) << 16);
}

// ---------- async global->LDS, 16B per lane ----------
__device__ __forceinline__ void load16(const u16* g, u16* l) {
    __builtin_amdgcn_global_load_lds(
        (__attribute__((address_space(1))) void*)(u16*)g,
        (__attribute__((address_space(3))) void*)l,
        16, 0, 0);
}

// ============================================================
// x[8,256,56,56] f32 -> x_tp[8,58,58,256] bf16, zero-padded border.
// ============================================================
__global__ __launch_bounds__(256) void k_xtp(const float* __restrict__ x,
                                             u16* __restrict__ xtp) {
    const int bh = blockIdx.x;          // 8*58
    const int b = bh / 58;
    const int hp = bh - b * 58;
    const int tid = threadIdx.x;
    u16* rowbase = xtp + (size_t)(b * 58 + hp) * 58 * 256;
    if (hp == 0 || hp == 57) {
        u32* p = (u32*)rowbase;
        for (int i = tid; i < 58 * 128; i += 256) p[i] = 0;
        return;
    }
    __shared__ float lds[256 * 57];
    const int h = hp - 1;
    const float* xb = x + (size_t)b * 802816 + h * 56;
    for (int idx = tid; idx < 256 * 56; idx += 256) {
        int c = idx / 56;
        int w = idx - c * 56;
        lds[c * 57 + w] = xb[c * 3136 + w];
    }
    __syncthreads();
    rowbase[tid] = 0;
    rowbase[57 * 256 + tid] = 0;
    for (int wp = 1; wp <= 56; ++wp)
        rowbase[wp * 256 + tid] = f2b(lds[tid * 57 + (wp - 1)]);
}

// ============================================================
// Merged weight prep (one kernel, range dispatch).
// d' = rr*256 + c  <->  d = c*9 + rr
// W1f/W3f: [w:4][kc72:72][j:4][lane:64][e:8] ; W2f: [rr:9][w:4][kc:8][j:4][lane:64][e:8]
// ============================================================
__device__ __forceinline__ void wpack13(const float* in, u16* out, int idx) {
    int e = idx & 7;
    int lane = (idx >> 3) & 63;
    int j = (idx >> 9) & 3;
    int g = idx >> 11;            // w*72 + kc72
    int w = g / 72;
    int kc = g - w * 72;
    int n = w * 64 + j * 16 + (lane & 15);
    int kp = kc * 32 + (lane >> 4) * 8 + e;
    int d = (kp & 255) * 9 + (kp >> 8);
    out[idx] = f2b(in[d * 256 + n]);
}
__global__ void k_wprep(const float* __restrict__ W1, const float* __restrict__ W2,
                        const float* __restrict__ W3, const float* __restrict__ b2,
                        u16* __restrict__ W1f, u16* __restrict__ W2f,
                        u16* __restrict__ W3f, float* __restrict__ b2p) {
    const int bid = blockIdx.x;
    const int tid = threadIdx.x;
    if (bid < 2304) {
        wpack13(W1, W1f, bid * 256 + tid);
    } else if (bid < 4608) {
        wpack13(W3, W3f, (bid - 2304) * 256 + tid);
    } else if (bid < 6912) {
        int idx = (bid - 4608) * 256 + tid;
        int e = idx & 7;
        int lane = (idx >> 3) & 63;
        int j = (idx >> 9) & 3;
        int kc = (idx >> 11) & 7;
        int g = idx >> 14;        // rr*4 + w
        int rr = g >> 2;
        int w = g & 3;
        int col = (j >> 1) * 128 + w * 32 + (j & 1) * 16 + (lane & 15);
        int np = rr * 256 + col;
        int d = (np & 255) * 9 + (np >> 8);
        int k = kc * 32 + (lane >> 4) * 8 + e;
        W2f[idx] = f2b(W2[k * 2304 + d]);
    } else {
        int idx = (bid - 6912) * 256 + tid;
        if (idx < 2304) b2p[idx] = b2[(idx & 255) * 9 + (idx >> 8)];
    }
}

// ============================================================
// Fused kernel, 32 rows/block (784 blocks):
//   phase1 : h1 = relu(t @ W1 + b1)   (A slab-staged, B-frags from L2, h1->LDS)
//   per rr : z = h1 @ W2slab          (K=256, no barriers)
//            per half: u = t*sigmoid(z+b2) (scalar t-gather, fused) -> Us
//                      accO += u @ W3slab-half (K=128)
//   epilogue: out = accO + b3
// ============================================================
__global__ __launch_bounds__(256, 3) void k_fused(
    const u16* __restrict__ xtp, const u16* __restrict__ W1f,
    const u16* __restrict__ W2f, const u16* __restrict__ W3f,
    const float* __restrict__ b1, const float* __restrict__ b2p,
    const float* __restrict__ b3, float* __restrict__ out) {
    __shared__ __align__(16) u16 As[8192];  // 16KB: A-slab staging, then h1 [kc:8][row:32][c:32]
    __shared__ __align__(16) u16 Us[4096];  // 8KB : u half [kc:4][row:32][c:32]

    const int tid = threadIdx.x;
    const int wave = tid >> 6;
    const int lane = tid & 63;
    const int fr = lane & 15;
    const int fq = lane >> 4;
    const int l0 = blockIdx.x * 32;

    // xtp row-base helper
    auto rowbase = [&](int l) {
        int b = l / 3136;
        int rem = l - b * 3136;
        int h = rem / 56;
        int w = rem - h * 56;
        return ((b * 58 + h + 1) * 58 + (w + 1)) * 256;
    };
    // staging bases: rows srow4 and srow4+16, + col (lane&3)*8
    const int srow4 = lane >> 2;
    const int aoffA = rowbase(l0 + srow4) + (lane & 3) * 8;
    const int aoffB = rowbase(l0 + 16 + srow4) + (lane & 3) * 8;
    // t-gather bases for rows i*16 + fq*4 + r
    int tb[8];
#pragma unroll
    for (int i = 0; i < 2; ++i)
#pragma unroll
        for (int r = 0; r < 4; ++r)
            tb[i * 4 + r] = rowbase(l0 + i * 16 + fq * 4 + r);

    accfrag_t acc[2][4];
#pragma unroll
    for (int i = 0; i < 2; ++i)
#pragma unroll
        for (int j = 0; j < 4; ++j) acc[i][j] = (accfrag_t)0.f;

    // ---------------- phase 1: h1 = relu(t @ W1 + b1) ----------------
    const u16* w1base = W1f + (size_t)wave * 147456 + lane * 8;
    const int kcA = wave * 2;      // this wave stages chunks kcA, kcA+1
    u16* ldsA = As + wave * 2048 + lane * 8;
    for (int rr = 0; rr < 9; ++rr) {
        const int shift = ((rr / 3 - 1) * 58 + (rr % 3) - 1) * 256;
        __syncthreads();   // prev slab's MFMA reads done
        load16(xtp + aoffA + shift + kcA * 32,        ldsA);
        load16(xtp + aoffB + shift + kcA * 32,        ldsA + 512);
        load16(xtp + aoffA + shift + kcA * 32 + 32,   ldsA + 1024);
        load16(xtp + aoffB + shift + kcA * 32 + 32,   ldsA + 1536);
        __syncthreads();   // slab visible
#pragma unroll
        for (int kc = 0; kc < 8; ++kc) {
            const u16* wb = w1base + (size_t)(rr * 8 + kc) * 2048;
            bfrag_t bf[4], af[2];
#pragma unroll
            for (int j = 0; j < 4; ++j)
                bf[j] = *(const bfrag_t*)(wb + j * 512);
#pragma unroll
            for (int i = 0; i < 2; ++i)
                af[i] = *(const bfrag_t*)(As + kc * 1024 + (i * 16 + fr) * 32 + fq * 8);
#pragma unroll
            for (int i = 0; i < 2; ++i)
#pragma unroll
                for (int j = 0; j < 4; ++j)
                    acc[i][j] = __builtin_amdgcn_mfma_f32_16x16x32_bf16(
                        af[i], bf[j], acc[i][j], 0, 0, 0);
        }
    }
    // h1 epilogue: relu, pair-pack, chunk-major into As arena
    __syncthreads();
#pragma unroll
    for (int i = 0; i < 2; ++i) {
#pragma unroll
        for (int j = 0; j < 4; ++j) {
            const int col = wave * 64 + j * 16 + fr;
            const float bv = b1[col];
#pragma unroll
            for (int r = 0; r < 4; ++r) {
                float v = acc[i][j][r] + bv;
                v = v > 0.f ? v : 0.f;
                const float vh = __shfl_down(v, 1);
                if (!(lane & 1)) {
                    u32 pk = (u32)f2b(v) | ((u32)f2b(vh) << 16);
                    *(u32*)&As[(col >> 5) * 1024 + (i * 16 + fq * 4 + r) * 32 + (col & 31)] = pk;
                }
            }
        }
    }
    __syncthreads();

    accfrag_t accO[2][4];
#pragma unroll
    for (int i = 0; i < 2; ++i)
#pragma unroll
        for (int j = 0; j < 4; ++j) accO[i][j] = (accfrag_t)0.f;

    // ---------------- phase 2: per rr slab ----------------
    const u16* w3base = W3f + (size_t)wave * 147456 + lane * 8;
    for (int rr = 0; rr < 9; ++rr) {
        const int shift = ((rr / 3 - 1) * 58 + (rr % 3) - 1) * 256;
        // 2a: z = h1 @ W2slab (K=256, barrier-free)
#pragma unroll
        for (int i = 0; i < 2; ++i)
#pragma unroll
            for (int j = 0; j < 4; ++j) acc[i][j] = (accfrag_t)0.f;
        const u16* w2base = W2f + (size_t)(rr * 4 + wave) * 16384 + lane * 8;
#pragma unroll
        for (int kc = 0; kc < 8; ++kc) {
            bfrag_t bf[4], af[2];
#pragma unroll
            for (int j = 0; j < 4; ++j)
                bf[j] = *(const bfrag_t*)(w2base + (kc * 4 + j) * 512);
#pragma unroll
            for (int i = 0; i < 2; ++i)
                af[i] = *(const bfrag_t*)(As + kc * 1024 + (i * 16 + fr) * 32 + fq * 8);
#pragma unroll
            for (int i = 0; i < 2; ++i)
#pragma unroll
                for (int j = 0; j < 4; ++j)
                    acc[i][j] = __builtin_amdgcn_mfma_f32_16x16x32_bf16(
                        af[i], bf[j], acc[i][j], 0, 0, 0);
        }
        // halves: fused sigmoid + t-gather-multiply -> Us, then GEMM3 accumulate
#pragma unroll
        for (int h = 0; h < 2; ++h) {
            __syncthreads();  // prev-half 2b reads of Us done
#pragma unroll
            for (int i = 0; i < 2; ++i) {
#pragma unroll
                for (int jj = 0; jj < 2; ++jj) {
                    const int j = h * 2 + jj;
                    const int colh = wave * 32 + jj * 16 + fr;
                    const float bv = b2p[rr * 256 + h * 128 + colh];
                    const int goff = shift + h * 128 + colh;
#pragma unroll
                    for (int r = 0; r < 4; ++r) {
                        const float z = acc[i][j][r] + bv;
                        const float s = 1.f / (1.f + __expf(-z));
                        const float tv = b2f(xtp[tb[i * 4 + r] + goff]);
                        const float u = s * tv;
                        const float uh = __shfl_down(u, 1);
                        if (!(lane & 1)) {
                            u32 pk = (u32)f2b(u) | ((u32)f2b(uh) << 16);
                            *(u32*)&Us[(colh >> 5) * 1024 +
                                       (i * 16 + fq * 4 + r) * 32 + (colh & 31)] = pk;
                        }
                    }
                }
            }
            __syncthreads();  // u visible
            // 2b: accO += u @ W3slab-half (K=128)
#pragma unroll
            for (int kc = 0; kc < 4; ++kc) {
                const u16* wb = w3base + (size_t)(rr * 8 + h * 4 + kc) * 2048;
                bfrag_t bf[4], af[2];
#pragma unroll
                for (int j = 0; j < 4; ++j)
                    bf[j] = *(const bfrag_t*)(wb + j * 512);
#pragma unroll
                for (int i = 0; i < 2; ++i)
                    af[i] = *(const bfrag_t*)(Us + kc * 1024 + (i * 16 + fr) * 32 + fq * 8);
#pragma unroll
                for (int i = 0; i < 2; ++i)
#pragma unroll
                    for (int j = 0; j < 4; ++j)
                        accO[i][j] = __builtin_amdgcn_mfma_f32_16x16x32_bf16(
                            af[i], bf[j], accO[i][j], 0, 0, 0);
            }
        }
    }

    // ---------------- final epilogue: out = accO + b3 ----------------
#pragma unroll
    for (int i = 0; i < 2; ++i) {
#pragma unroll
        for (int j = 0; j < 4; ++j) {
            const int col = wave * 64 + j * 16 + fr;
            const float bv = b3[col];
#pragma unroll
            for (int r = 0; r < 4; ++r) {
                const float v = accO[i][j][r] + bv;
                const float vh = __shfl_down(v, 1);
                if (!(lane & 1)) {
                    float2 st = make_float2(v, vh);
                    *(float2*)(out + (size_t)(l0 + i * 16 + fq * 4 + r) * 256 + col) = st;
                }
            }
        }
    }
}

extern "C" void kernel_launch(void* const* d_in, const int* in_sizes, int n_in,
                              void* d_out, int out_size, void* d_ws, size_t ws_size,
                              hipStream_t stream) {
    const float* x  = (const float*)d_in[0];
    const float* W1 = (const float*)d_in[1];
    const float* b1 = (const float*)d_in[2];
    const float* W2 = (const float*)d_in[3];
    const float* b2 = (const float*)d_in[4];
    const float* W3 = (const float*)d_in[5];
    const float* b3 = (const float*)d_in[6];
    float* out = (float*)d_out;

    char* ws = (char*)d_ws;
    u16* xtp = (u16*)ws;  ws += (size_t)8 * 58 * 58 * 256 * 2;
    u16* W1f = (u16*)ws;  ws += (size_t)589824 * 2;
    u16* W2f = (u16*)ws;  ws += (size_t)589824 * 2;
    u16* W3f = (u16*)ws;  ws += (size_t)589824 * 2;
    float* b2p = (float*)ws;

    k_wprep<<<6921, 256, 0, stream>>>(W1, W2, W3, b2, W1f, W2f, W3f, b2p);
    k_xtp<<<464, 256, 0, stream>>>(x, xtp);
    k_fused<<<784, 256, 0, stream>>>(xtp, W1f, W2f, W3f, b1, b2p, b3, out);
}

// Round 6
// 229.791 us; speedup vs baseline: 1.6064x; 1.6064x over previous
//
#include <hip/hip_runtime.h>

typedef unsigned short u16;
typedef unsigned int u32;
typedef __attribute__((ext_vector_type(8))) short bfrag_t;   // 8 bf16 (4 VGPRs)
typedef __attribute__((ext_vector_type(4))) float accfrag_t; // 4 fp32

// ---------- bf16 helpers (RNE) ----------
__device__ __forceinline__ u16 f2b(float f) {
    u32 u = __float_as_uint(f);
    u32 r = (u + 0x7FFFu + ((u >> 16) & 1u)) >> 16;
    return (u16)r;
}
__device__ __forceinline__ float b2f(u16 b) {
    return __uint_as_float(((u32)b) << 16);
}

// ---------- async global->LDS, 16B per lane ----------
__device__ __forceinline__ void load16(const u16* g, u16* l) {
    __builtin_amdgcn_global_load_lds(
        (__attribute__((address_space(1))) void*)(u16*)g,
        (__attribute__((address_space(3))) void*)l,
        16, 0, 0);
}

// ============================================================
// x[8,256,56,56] f32 -> x_tp[8,58,58,256] bf16, zero-padded border.
// ============================================================
__global__ __launch_bounds__(256) void k_xtp(const float* __restrict__ x,
                                             u16* __restrict__ xtp) {
    const int bh = blockIdx.x;          // 8*58
    const int b = bh / 58;
    const int hp = bh - b * 58;
    const int tid = threadIdx.x;
    u16* rowbase = xtp + (size_t)(b * 58 + hp) * 58 * 256;
    if (hp == 0 || hp == 57) {
        u32* p = (u32*)rowbase;
        for (int i = tid; i < 58 * 128; i += 256) p[i] = 0;
        return;
    }
    __shared__ float lds[256 * 57];
    const int h = hp - 1;
    const float* xb = x + (size_t)b * 802816 + h * 56;
    for (int idx = tid; idx < 256 * 56; idx += 256) {
        int c = idx / 56;
        int w = idx - c * 56;
        lds[c * 57 + w] = xb[c * 3136 + w];
    }
    __syncthreads();
    rowbase[tid] = 0;
    rowbase[57 * 256 + tid] = 0;
    for (int wp = 1; wp <= 56; ++wp)
        rowbase[wp * 256 + tid] = f2b(lds[tid * 57 + (wp - 1)]);
}

// ============================================================
// Coalesced weight prep (one kernel, 225 blocks).
// d' = rr*256 + c  <->  d = c*9 + rr
// W1f/W3f: [w:8][kc72:72][j:2][lane:64][e:8]
// W2f    : [rr:9][w:8][kc:8][j:2][lane:64][e:8]
// ============================================================
__global__ __launch_bounds__(256) void k_wprep(
    const float* __restrict__ W1, const float* __restrict__ W2,
    const float* __restrict__ W3, const float* __restrict__ b2,
    u16* __restrict__ W1f, u16* __restrict__ W2f,
    u16* __restrict__ W3f, float* __restrict__ b2p) {
    const int bid = blockIdx.x;
    const int tid = threadIdx.x;
    if (bid < 144) {             // W1 (0..71) / W3 (72..143)
        const float* in = bid < 72 ? W1 : W3;
        u16* out = bid < 72 ? W1f : W3f;
        const int b = bid < 72 ? bid : bid - 72;
        const int rrp = b >> 3;          // 0..8
        const int cg = b & 7;            // c-group of 32
        __shared__ u16 lds1[8192];       // [cc:32][n:256]
        for (int cc = 0; cc < 32; ++cc) {
            int d = (cg * 32 + cc) * 9 + rrp;
            lds1[cc * 256 + tid] = f2b(in[d * 256 + tid]);
        }
        __syncthreads();
        const int kc72 = rrp * 8 + cg;
        const int w = tid >> 5;
        const int j = (tid >> 4) & 1;
        u16* ob = out + (w * 72 + kc72) * 1024 + ((tid * 32) & 1023);
        for (int s = 0; s < 32; ++s) {
            int o = tid * 32 + s;
            int e = o & 7, ln = (o >> 3) & 63;
            int n = w * 32 + j * 16 + (ln & 15);
            int q = (ln >> 4) * 8 + e;
            ob[s] = lds1[q * 256 + n];
        }
    } else if (bid < 216) {      // W2
        const int b = bid - 144;
        const int rr = b >> 3;
        const int w = b & 7;
        __shared__ u16 lds2[8192];       // [k:256][dloc:32]
        for (int s = 0; s < 32; ++s) {
            int li = s * 256 + tid;
            int k = li >> 5, dloc = li & 31;
            lds2[k * 32 + dloc] = f2b(W2[k * 2304 + (w * 32 + dloc) * 9 + rr]);
        }
        __syncthreads();
        u16* ob = W2f + (rr * 8 + w) * 8192 + tid * 32;
        for (int s = 0; s < 32; ++s) {
            int o = tid * 32 + s;
            int e = o & 7, ln = (o >> 3) & 63, j = (o >> 9) & 1, kc = o >> 10;
            int k = kc * 32 + (ln >> 4) * 8 + e;
            int dloc = j * 16 + (ln & 15);
            ob[s] = lds2[k * 32 + dloc];
        }
    } else {                     // b2 permute (9 blocks)
        int idx = (bid - 216) * 256 + tid;
        if (idx < 2304) b2p[idx] = b2[(idx & 255) * 9 + (idx >> 8)];
    }
}

// ============================================================
// Fused kernel: 392 blocks x 512 threads (8 waves), 64 rows/block,
// column-split 8 x 32. B-frags direct from L2 (frag-packed weights).
//   phase1 : h1 = relu(t @ W1 + b1)  (t slab-staged via load16; h1 -> LDS)
//   per rr : z = h1 @ W2slab (K=256, barrier-free A from LDS)
//            sigmoid pack -> Us ; vector u = t*s (b128) ; accO += u @ W3slab
//   epilogue: out = accO + b3
// ============================================================
__global__ __launch_bounds__(512, 4) void k_fused(
    const u16* __restrict__ xtp, const u16* __restrict__ W1f,
    const u16* __restrict__ W2f, const u16* __restrict__ W3f,
    const float* __restrict__ b1, const float* __restrict__ b2p,
    const float* __restrict__ b3, float* __restrict__ out) {
    __shared__ __align__(16) u16 As[16384];  // 32KB: t-slab staging, then h1 [kc:8][row:64][c:32]
    __shared__ __align__(16) u16 Us[16384];  // 32KB: s then u          [kc:8][row:64][c:32]

    const int tid = threadIdx.x;
    const int wave = tid >> 6;
    const int lane = tid & 63;
    const int fr = lane & 15;
    const int fq = lane >> 4;
    const int l0 = blockIdx.x * 64;

    // staging / u-pass mapping: row=(tid>>2)&63, c8=(tid&3)*8, kc=2q+(tid>>8)
    const int srow = (tid >> 2) & 63;
    const int hi = tid >> 8;
    int roff;
    {
        int l = l0 + srow;
        int b = l / 3136;
        int rem = l - b * 3136;
        int h = rem / 56;
        int w = rem - h * 56;
        roff = ((b * 58 + h + 1) * 58 + (w + 1)) * 256 + (tid & 3) * 8;
    }
    u16* ldsStage = As + (wave & 3) * 512 + lane * 8;   // + kc*2048

    accfrag_t acc[4][2], accO[4][2];
#pragma unroll
    for (int i = 0; i < 4; ++i)
#pragma unroll
        for (int j = 0; j < 2; ++j) {
            acc[i][j] = (accfrag_t)0.f;
            accO[i][j] = (accfrag_t)0.f;
        }

    // ---------------- phase 1: h1 = relu(t @ W1 + b1) ----------------
    const u16* w1p = W1f + wave * 73728 + lane * 8;
    for (int rr = 0; rr < 9; ++rr) {
        const int shift = ((rr / 3 - 1) * 58 + (rr % 3) - 1) * 256;
        __syncthreads();   // prev slab's MFMA reads done
#pragma unroll
        for (int q = 0; q < 4; ++q) {
            const int kc = 2 * q + hi;
            load16(xtp + roff + shift + kc * 32, ldsStage + kc * 2048);
        }
        __syncthreads();   // slab visible
#pragma unroll
        for (int kc = 0; kc < 8; ++kc) {
            bfrag_t bf[2], af[4];
#pragma unroll
            for (int j = 0; j < 2; ++j)
                bf[j] = *(const bfrag_t*)(w1p + ((rr * 8 + kc) * 2 + j) * 512);
#pragma unroll
            for (int i = 0; i < 4; ++i)
                af[i] = *(const bfrag_t*)(As + kc * 2048 + (i * 16 + fr) * 32 + fq * 8);
#pragma unroll
            for (int i = 0; i < 4; ++i)
#pragma unroll
                for (int j = 0; j < 2; ++j)
                    acc[i][j] = __builtin_amdgcn_mfma_f32_16x16x32_bf16(
                        af[i], bf[j], acc[i][j], 0, 0, 0);
        }
    }
    // h1 epilogue: relu, pair-pack, chunk-major into As
    __syncthreads();
#pragma unroll
    for (int i = 0; i < 4; ++i) {
#pragma unroll
        for (int j = 0; j < 2; ++j) {
            const int col = wave * 32 + j * 16 + fr;
            const float bv = b1[col];
#pragma unroll
            for (int r = 0; r < 4; ++r) {
                float v = acc[i][j][r] + bv;
                v = v > 0.f ? v : 0.f;
                const float vh = __shfl_down(v, 1);
                if (!(lane & 1)) {
                    u32 pk = (u32)f2b(v) | ((u32)f2b(vh) << 16);
                    *(u32*)&As[wave * 2048 + (i * 16 + fq * 4 + r) * 32 + j * 16 + fr] = pk;
                }
            }
        }
    }
    __syncthreads();

    // ---------------- phase 2: per rr slab ----------------
    const u16* w3p = W3f + wave * 73728 + lane * 8;
    for (int rr = 0; rr < 9; ++rr) {
        const int shift = ((rr / 3 - 1) * 58 + (rr % 3) - 1) * 256;
        // 2a: z = h1 @ W2slab (K=256, barrier-free)
#pragma unroll
        for (int i = 0; i < 4; ++i)
#pragma unroll
            for (int j = 0; j < 2; ++j) acc[i][j] = (accfrag_t)0.f;
        const u16* w2p = W2f + (rr * 8 + wave) * 8192 + lane * 8;
#pragma unroll
        for (int kc = 0; kc < 8; ++kc) {
            bfrag_t bf[2], af[4];
#pragma unroll
            for (int j = 0; j < 2; ++j)
                bf[j] = *(const bfrag_t*)(w2p + (kc * 2 + j) * 512);
#pragma unroll
            for (int i = 0; i < 4; ++i)
                af[i] = *(const bfrag_t*)(As + kc * 2048 + (i * 16 + fr) * 32 + fq * 8);
#pragma unroll
            for (int i = 0; i < 4; ++i)
#pragma unroll
                for (int j = 0; j < 2; ++j)
                    acc[i][j] = __builtin_amdgcn_mfma_f32_16x16x32_bf16(
                        af[i], bf[j], acc[i][j], 0, 0, 0);
        }
        __syncthreads();  // prev rr's 2b reads of Us done
        // sigmoid pair-pack -> Us
#pragma unroll
        for (int i = 0; i < 4; ++i) {
#pragma unroll
            for (int j = 0; j < 2; ++j) {
                const int colh = wave * 32 + j * 16 + fr;
                const float bv = b2p[rr * 256 + colh];
#pragma unroll
                for (int r = 0; r < 4; ++r) {
                    const float z = acc[i][j][r] + bv;
                    const float s = 1.f / (1.f + __expf(-z));
                    const float sh = __shfl_down(s, 1);
                    if (!(lane & 1)) {
                        u32 pk = (u32)f2b(s) | ((u32)f2b(sh) << 16);
                        *(u32*)&Us[wave * 2048 + (i * 16 + fq * 4 + r) * 32 + j * 16 + fr] = pk;
                    }
                }
            }
        }
        __syncthreads();  // s visible
        // vector u-pass: u = t * s (b128 LDS read + b128 global + b128 LDS write)
#pragma unroll
        for (int q = 0; q < 4; ++q) {
            const int kc = 2 * q + hi;
            const int idx = kc * 2048 + ((tid * 8) & 2047);
            bfrag_t sv = *(const bfrag_t*)(Us + idx);
            bfrag_t tv = *(const bfrag_t*)(xtp + roff + shift + kc * 32);
            bfrag_t rv;
#pragma unroll
            for (int e = 0; e < 8; ++e)
                rv[e] = (short)f2b(b2f((u16)sv[e]) * b2f((u16)tv[e]));
            *(bfrag_t*)(Us + idx) = rv;
        }
        __syncthreads();  // u visible
        // 2b: accO += u @ W3slab (K=256)
#pragma unroll
        for (int kc = 0; kc < 8; ++kc) {
            bfrag_t bf[2], af[4];
#pragma unroll
            for (int j = 0; j < 2; ++j)
                bf[j] = *(const bfrag_t*)(w3p + ((rr * 8 + kc) * 2 + j) * 512);
#pragma unroll
            for (int i = 0; i < 4; ++i)
                af[i] = *(const bfrag_t*)(Us + kc * 2048 + (i * 16 + fr) * 32 + fq * 8);
#pragma unroll
            for (int i = 0; i < 4; ++i)
#pragma unroll
                for (int j = 0; j < 2; ++j)
                    accO[i][j] = __builtin_amdgcn_mfma_f32_16x16x32_bf16(
                        af[i], bf[j], accO[i][j], 0, 0, 0);
        }
    }

    // ---------------- final epilogue: out = accO + b3 ----------------
#pragma unroll
    for (int i = 0; i < 4; ++i) {
#pragma unroll
        for (int j = 0; j < 2; ++j) {
            const int col = wave * 32 + j * 16 + fr;
            const float bv = b3[col];
#pragma unroll
            for (int r = 0; r < 4; ++r) {
                const float v = accO[i][j][r] + bv;
                const float vh = __shfl_down(v, 1);
                if (!(lane & 1)) {
                    float2 st = make_float2(v, vh);
                    *(float2*)(out + (size_t)(l0 + i * 16 + fq * 4 + r) * 256 + col) = st;
                }
            }
        }
    }
}

extern "C" void kernel_launch(void* const* d_in, const int* in_sizes, int n_in,
                              void* d_out, int out_size, void* d_ws, size_t ws_size,
                              hipStream_t stream) {
    const float* x  = (const float*)d_in[0];
    const float* W1 = (const float*)d_in[1];
    const float* b1 = (const float*)d_in[2];
    const float* W2 = (const float*)d_in[3];
    const float* b2 = (const float*)d_in[4];
    const float* W3 = (const float*)d_in[5];
    const float* b3 = (const float*)d_in[6];
    float* out = (float*)d_out;

    char* ws = (char*)d_ws;
    u16* xtp = (u16*)ws;  ws += (size_t)8 * 58 * 58 * 256 * 2;
    u16* W1f = (u16*)ws;  ws += (size_t)589824 * 2;
    u16* W2f = (u16*)ws;  ws += (size_t)589824 * 2;
    u16* W3f = (u16*)ws;  ws += (size_t)589824 * 2;
    float* b2p = (float*)ws;

    k_wprep<<<225, 256, 0, stream>>>(W1, W2, W3, b2, W1f, W2f, W3f, b2p);
    k_xtp<<<464, 256, 0, stream>>>(x, xtp);
    k_fused<<<392, 512, 0, stream>>>(xtp, W1f, W2f, W3f, b1, b2p, b3, out);
}

// Round 7
// 205.860 us; speedup vs baseline: 1.7932x; 1.1162x over previous
//
#include <hip/hip_runtime.h>

typedef unsigned short u16;
typedef unsigned int u32;
typedef __attribute__((ext_vector_type(8))) short bfrag_t;   // 8 bf16 (4 VGPRs)
typedef __attribute__((ext_vector_type(4))) float accfrag_t; // 4 fp32
typedef __attribute__((ext_vector_type(4))) u32 u32x4;

// ---------- bf16 helpers ----------
__device__ __forceinline__ u16 f2b(float f) {
    u32 u = __float_as_uint(f);
    u32 r = (u + 0x7FFFu + ((u >> 16) & 1u)) >> 16;
    return (u16)r;
}
// pack 2 f32 -> 2 bf16 in one instruction (lo -> bits[15:0], hi -> bits[31:16])
__device__ __forceinline__ u32 pkbf16(float lo, float hi) {
    u32 r;
    asm("v_cvt_pk_bf16_f32 %0, %1, %2" : "=v"(r) : "v"(lo), "v"(hi));
    return r;
}
__device__ __forceinline__ float blo(u32 v) { return __uint_as_float(v << 16); }
__device__ __forceinline__ float bhi(u32 v) { return __uint_as_float(v & 0xffff0000u); }

// ---------- async global->LDS, 16B per lane ----------
__device__ __forceinline__ void load16(const u16* g, u16* l) {
    __builtin_amdgcn_global_load_lds(
        (__attribute__((address_space(1))) void*)(u16*)g,
        (__attribute__((address_space(3))) void*)l,
        16, 0, 0);
}

// ============================================================
// Merged prep: range dispatch, 689 blocks.
//   0..463  : x[8,256,56,56] f32 -> x_tp[8,58,58,256] bf16 (zero-pad border)
//   464..607: W1/W3 frag-pack   608..679: W2 frag-pack   680..688: b2 permute
// All global writes coalesced; permutation gathered from LDS.
// d' = rr*256 + c  <->  d = c*9 + rr
// W1f/W3f: [w:8][kc72:72][j:2][lane:64][e:8] ; W2f: [rr:9][w:8][kc:8][j:2][lane:64][e:8]
// ============================================================
__global__ __launch_bounds__(256) void k_prep(
    const float* __restrict__ x, const float* __restrict__ W1,
    const float* __restrict__ W2, const float* __restrict__ W3,
    const float* __restrict__ b2, u16* __restrict__ xtp,
    u16* __restrict__ W1f, u16* __restrict__ W2f,
    u16* __restrict__ W3f, float* __restrict__ b2p) {
    __shared__ __align__(16) char smem[58368];
    const int bid = blockIdx.x;
    const int tid = threadIdx.x;
    if (bid < 464) {             // ---- xtp ----
        const int b = bid / 58;
        const int hp = bid - b * 58;
        u16* rowbase = xtp + (size_t)(b * 58 + hp) * 58 * 256;
        if (hp == 0 || hp == 57) {
            u32* p = (u32*)rowbase;
            for (int i = tid; i < 58 * 128; i += 256) p[i] = 0;
            return;
        }
        float* lds = (float*)smem;       // [c:256][w:57]
        const int h = hp - 1;
        const float* xb = x + (size_t)b * 802816 + h * 56;
        for (int idx = tid; idx < 256 * 56; idx += 256) {
            int c = idx / 56;
            int w = idx - c * 56;
            lds[c * 57 + w] = xb[c * 3136 + w];
        }
        __syncthreads();
        rowbase[tid] = 0;
        rowbase[57 * 256 + tid] = 0;
        for (int wp = 1; wp <= 56; ++wp)
            rowbase[wp * 256 + tid] = f2b(lds[tid * 57 + (wp - 1)]);
    } else if (bid < 608) {      // ---- W1 / W3 pack ----
        int b = bid - 464;
        const float* in = b < 72 ? W1 : W3;
        u16* out = b < 72 ? W1f : W3f;
        if (b >= 72) b -= 72;
        const int rrp = b >> 3;          // 0..8
        const int cg = b & 7;            // c-group of 32
        u16* lds1 = (u16*)smem;          // [q:32][n:256]
        for (int cc = 0; cc < 32; ++cc) {
            int d = (cg * 32 + cc) * 9 + rrp;
            lds1[cc * 256 + tid] = f2b(in[d * 256 + tid]);
        }
        __syncthreads();
        const int kc72 = rrp * 8 + cg;
        for (int s = 0; s < 32; ++s) {
            const int w = s >> 2;
            const int o = (s & 3) * 256 + tid;    // 0..1023 within [j][lane][e]
            const int e = o & 7;
            const int ln = (o >> 3) & 63;
            const int j = o >> 9;
            const int n = w * 32 + j * 16 + (ln & 15);
            const int q = (ln >> 4) * 8 + e;
            out[(w * 72 + kc72) * 1024 + o] = lds1[q * 256 + n];
        }
    } else if (bid < 680) {      // ---- W2 pack ----
        const int b = bid - 608;
        const int rr = b >> 3;
        const int w = b & 7;
        u16* lds2 = (u16*)smem;          // [k:256][dloc:32]
        for (int s = 0; s < 32; ++s) {
            int li = s * 256 + tid;
            int k = li >> 5, dloc = li & 31;
            lds2[k * 32 + dloc] = f2b(W2[k * 2304 + (w * 32 + dloc) * 9 + rr]);
        }
        __syncthreads();
        u16* ob = W2f + (rr * 8 + w) * 8192;
        for (int s = 0; s < 32; ++s) {
            const int o = s * 256 + tid;          // 0..8191
            const int e = o & 7;
            const int ln = (o >> 3) & 63;
            const int j = (o >> 9) & 1;
            const int kc = o >> 10;
            const int k = kc * 32 + (ln >> 4) * 8 + e;
            const int dloc = j * 16 + (ln & 15);
            ob[o] = lds2[k * 32 + dloc];
        }
    } else {                     // ---- b2 permute ----
        int idx = (bid - 680) * 256 + tid;
        if (idx < 2304) b2p[idx] = b2[(idx & 255) * 9 + (idx >> 8)];
    }
}

// ============================================================
// Fused kernel: 392 blocks x 512 threads (8 waves), 64 rows/block,
// column-split 8 x 32. B-frags direct from L2 (frag-packed weights).
//   phase1 : h1 = relu(t @ W1 + b1)   double-buffered slab staging (As/Us)
//   per rr : tv-prefetch -> z = h1 @ W2slab (barrier-free)
//            sigmoid pack -> Us ; u = t*s (dword math) ; accO += u @ W3slab
//   epilogue: out = accO + b3
// ============================================================
__global__ __launch_bounds__(512, 4) void k_fused(
    const u16* __restrict__ xtp, const u16* __restrict__ W1f,
    const u16* __restrict__ W2f, const u16* __restrict__ W3f,
    const float* __restrict__ b1, const float* __restrict__ b2p,
    const float* __restrict__ b3, float* __restrict__ out) {
    __shared__ __align__(16) u16 As[16384];  // 32KB: t-slab buf0, then h1 [kc:8][row:64][c:32]
    __shared__ __align__(16) u16 Us[16384];  // 32KB: t-slab buf1, then s/u [kc:8][row:64][c:32]

    const int tid = threadIdx.x;
    const int wave = tid >> 6;
    const int lane = tid & 63;
    const int fr = lane & 15;
    const int fq = lane >> 4;
    const int l0 = blockIdx.x * 64;
    const int hi = tid >> 8;

    // staging / u-pass mapping: row=(tid>>2)&63, c8=(tid&3)*8, kc=2q+hi
    int roff;
    {
        int l = l0 + ((tid >> 2) & 63);
        int b = l / 3136;
        int rem = l - b * 3136;
        int h = rem / 56;
        int w = rem - h * 56;
        roff = ((b * 58 + h + 1) * 58 + (w + 1)) * 256 + (tid & 3) * 8;
    }
    const int stageOff = (wave & 3) * 512 + lane * 8;
    auto shiftOf = [](int rr) { return ((rr / 3 - 1) * 58 + (rr % 3) - 1) * 256; };
    auto stage = [&](u16* buf, int shift) {
#pragma unroll
        for (int q = 0; q < 4; ++q) {
            const int kc = 2 * q + hi;
            load16(xtp + roff + shift + kc * 32, buf + kc * 2048 + stageOff);
        }
    };

    accfrag_t acc[4][2], accO[4][2];
#pragma unroll
    for (int i = 0; i < 4; ++i)
#pragma unroll
        for (int j = 0; j < 2; ++j) {
            acc[i][j] = (accfrag_t)0.f;
            accO[i][j] = (accfrag_t)0.f;
        }

    // ---------------- phase 1: h1 = relu(t @ W1 + b1), double-buffered ----
    const u16* w1p = W1f + wave * 73728 + lane * 8;
    stage(As, shiftOf(0));
    for (int rr = 0; rr < 9; ++rr) {
        u16* cur = (rr & 1) ? Us : As;
        u16* nxt = (rr & 1) ? As : Us;
        __syncthreads();   // cur slab visible (and nxt's readers from rr-1 done)
        if (rr < 8) stage(nxt, shiftOf(rr + 1));   // in flight during MFMA
#pragma unroll
        for (int kc = 0; kc < 8; ++kc) {
            bfrag_t bf[2], af[4];
#pragma unroll
            for (int j = 0; j < 2; ++j)
                bf[j] = *(const bfrag_t*)(w1p + ((rr * 8 + kc) * 2 + j) * 512);
#pragma unroll
            for (int i = 0; i < 4; ++i)
                af[i] = *(const bfrag_t*)(cur + kc * 2048 + (i * 16 + fr) * 32 + fq * 8);
#pragma unroll
            for (int i = 0; i < 4; ++i)
#pragma unroll
                for (int j = 0; j < 2; ++j)
                    acc[i][j] = __builtin_amdgcn_mfma_f32_16x16x32_bf16(
                        af[i], bf[j], acc[i][j], 0, 0, 0);
        }
    }
    // h1 epilogue: relu, pair-pack (cvt_pk), chunk-major into As
    __syncthreads();
#pragma unroll
    for (int i = 0; i < 4; ++i) {
#pragma unroll
        for (int j = 0; j < 2; ++j) {
            const float bv = b1[wave * 32 + j * 16 + fr];
#pragma unroll
            for (int r = 0; r < 4; ++r) {
                float v = acc[i][j][r] + bv;
                v = v > 0.f ? v : 0.f;
                const float vh = __shfl_down(v, 1);
                if (!(lane & 1))
                    *(u32*)&As[wave * 2048 + (i * 16 + fq * 4 + r) * 32 + j * 16 + fr] =
                        pkbf16(v, vh);
            }
        }
    }
    __syncthreads();

    // ---------------- phase 2: per rr slab ----------------
    const u16* w3p = W3f + wave * 73728 + lane * 8;
    for (int rr = 0; rr < 9; ++rr) {
        const int shift = shiftOf(rr);
        // tv prefetch (independent of 2a) — hidden under the MFMA below
        u32x4 tvreg[4];
#pragma unroll
        for (int q = 0; q < 4; ++q) {
            const int kc = 2 * q + hi;
            tvreg[q] = *(const u32x4*)(xtp + roff + shift + kc * 32);
        }
        // 2a: z = h1 @ W2slab (K=256, barrier-free)
#pragma unroll
        for (int i = 0; i < 4; ++i)
#pragma unroll
            for (int j = 0; j < 2; ++j) acc[i][j] = (accfrag_t)0.f;
        const u16* w2p = W2f + (rr * 8 + wave) * 8192 + lane * 8;
#pragma unroll
        for (int kc = 0; kc < 8; ++kc) {
            bfrag_t bf[2], af[4];
#pragma unroll
            for (int j = 0; j < 2; ++j)
                bf[j] = *(const bfrag_t*)(w2p + (kc * 2 + j) * 512);
#pragma unroll
            for (int i = 0; i < 4; ++i)
                af[i] = *(const bfrag_t*)(As + kc * 2048 + (i * 16 + fr) * 32 + fq * 8);
#pragma unroll
            for (int i = 0; i < 4; ++i)
#pragma unroll
                for (int j = 0; j < 2; ++j)
                    acc[i][j] = __builtin_amdgcn_mfma_f32_16x16x32_bf16(
                        af[i], bf[j], acc[i][j], 0, 0, 0);
        }
        __syncthreads();  // prev rr's 2b reads of Us done
        // sigmoid pair-pack -> Us
#pragma unroll
        for (int i = 0; i < 4; ++i) {
#pragma unroll
            for (int j = 0; j < 2; ++j) {
                const float bv = b2p[rr * 256 + wave * 32 + j * 16 + fr];
#pragma unroll
                for (int r = 0; r < 4; ++r) {
                    const float z = acc[i][j][r] + bv;
                    const float s = __builtin_amdgcn_rcpf(1.f + __expf(-z));
                    const float sh = __shfl_down(s, 1);
                    if (!(lane & 1))
                        *(u32*)&Us[wave * 2048 + (i * 16 + fq * 4 + r) * 32 + j * 16 + fr] =
                            pkbf16(s, sh);
                }
            }
        }
        __syncthreads();  // s visible
        // u = t * s  (dword math; each 16B chunk owned by one thread)
#pragma unroll
        for (int q = 0; q < 4; ++q) {
            const int kc = 2 * q + hi;
            const int idx = kc * 2048 + ((tid * 8) & 2047);
            u32x4 sv = *(const u32x4*)(Us + idx);
            u32x4 rv;
#pragma unroll
            for (int e = 0; e < 4; ++e)
                rv[e] = pkbf16(blo(sv[e]) * blo(tvreg[q][e]),
                               bhi(sv[e]) * bhi(tvreg[q][e]));
            *(u32x4*)(Us + idx) = rv;
        }
        __syncthreads();  // u visible
        // 2b: accO += u @ W3slab (K=256)
#pragma unroll
        for (int kc = 0; kc < 8; ++kc) {
            bfrag_t bf[2], af[4];
#pragma unroll
            for (int j = 0; j < 2; ++j)
                bf[j] = *(const bfrag_t*)(w3p + ((rr * 8 + kc) * 2 + j) * 512);
#pragma unroll
            for (int i = 0; i < 4; ++i)
                af[i] = *(const bfrag_t*)(Us + kc * 2048 + (i * 16 + fr) * 32 + fq * 8);
#pragma unroll
            for (int i = 0; i < 4; ++i)
#pragma unroll
                for (int j = 0; j < 2; ++j)
                    accO[i][j] = __builtin_amdgcn_mfma_f32_16x16x32_bf16(
                        af[i], bf[j], accO[i][j], 0, 0, 0);
        }
    }

    // ---------------- final epilogue: out = accO + b3 ----------------
#pragma unroll
    for (int i = 0; i < 4; ++i) {
#pragma unroll
        for (int j = 0; j < 2; ++j) {
            const int col = wave * 32 + j * 16 + fr;
            const float bv = b3[col];
#pragma unroll
            for (int r = 0; r < 4; ++r) {
                const float v = accO[i][j][r] + bv;
                const float vh = __shfl_down(v, 1);
                if (!(lane & 1)) {
                    float2 st = make_float2(v, vh);
                    *(float2*)(out + (size_t)(l0 + i * 16 + fq * 4 + r) * 256 + col) = st;
                }
            }
        }
    }
}

extern "C" void kernel_launch(void* const* d_in, const int* in_sizes, int n_in,
                              void* d_out, int out_size, void* d_ws, size_t ws_size,
                              hipStream_t stream) {
    const float* x  = (const float*)d_in[0];
    const float* W1 = (const float*)d_in[1];
    const float* b1 = (const float*)d_in[2];
    const float* W2 = (const float*)d_in[3];
    const float* b2 = (const float*)d_in[4];
    const float* W3 = (const float*)d_in[5];
    const float* b3 = (const float*)d_in[6];
    float* out = (float*)d_out;

    char* ws = (char*)d_ws;
    u16* xtp = (u16*)ws;  ws += (size_t)8 * 58 * 58 * 256 * 2;
    u16* W1f = (u16*)ws;  ws += (size_t)589824 * 2;
    u16* W2f = (u16*)ws;  ws += (size_t)589824 * 2;
    u16* W3f = (u16*)ws;  ws += (size_t)589824 * 2;
    float* b2p = (float*)ws;

    k_prep<<<689, 256, 0, stream>>>(x, W1, W2, W3, b2, xtp, W1f, W2f, W3f, b2p);
    k_fused<<<392, 512, 0, stream>>>(xtp, W1f, W2f, W3f, b1, b2p, b3, out);
}